// Round 11
// baseline (647.644 us; speedup 1.0000x reference)
//
#include <hip/hip_runtime.h>
#include <hip/hip_bf16.h>
#include <math.h>

typedef __attribute__((ext_vector_type(8))) short short8;   // 8 x bf16 (4 VGPRs)
typedef __attribute__((ext_vector_type(4))) float floatx4;  // MFMA C/D frag

static __device__ __forceinline__ unsigned short f2bf(float f) {
    unsigned int u = __float_as_uint(f);
    unsigned int r = (u + 0x7fffu + ((u >> 16) & 1u)) >> 16;   // RNE
    return (unsigned short)r;
}

// packed fp32x2 -> bf16x2 (RNE), single VALU inst (no builtin on gfx950)
static __device__ __forceinline__ unsigned int pk_bf16(float lo, float hi) {
    unsigned int r;
    asm("v_cvt_pk_bf16_f32 %0, %1, %2" : "=v"(r) : "v"(lo), "v"(hi));
    return r;
}

// async 16B global -> LDS copy (lds dest = wave-uniform base + lane*16)
static __device__ __forceinline__ void g2l16(const void* g, void* l) {
    __builtin_amdgcn_global_load_lds(
        (const __attribute__((address_space(1))) unsigned int*)g,
        (__attribute__((address_space(3))) unsigned int*)l,
        16, 0, 0);
}

static __device__ __forceinline__ float4 bnrelu4(float4 v, float4 s, float4 h) {
    float4 r;
    r.x = fmaxf(v.x * s.x + h.x, 0.f);
    r.y = fmaxf(v.y * s.y + h.y, 0.f);
    r.z = fmaxf(v.z * s.z + h.z, 0.f);
    r.w = fmaxf(v.w * s.w + h.w, 0.f);
    return r;
}

// ---------------------------------------------------------------------------
// Grouped bf16 MFMA GEMM, double-buffered, optional split-K.  (r9 version)
//   C[M,N] = A[M,K] @ W[N,K]^T
// fp32 A staged RAW into LDS via g2l16 (XOR-swizzled source), converted to
// bf16 with v_cvt_pk_bf16_f32 during fragment load; fuseA applies per-k BN
// +ReLU (tables indexed by TRUE k, not LDS slot).  bf16 A via g2l16.
// ksplit>1: atomicAdd fp32 partials into pre-zeroed Cf.
// ---------------------------------------------------------------------------
struct GDesc {
    const float*          Af;
    const unsigned short* Ab;
    const unsigned short* W;
    float*          Cf;
    unsigned short* Cb;
    const float *bias, *g, *b, *m, *v;
    int M, N, K;
    int Kreal;
    int fuse;
    int nbx;
    int block0;
    int nbb;
    int ksplit;
    int fuseA;
};
struct GArgs { GDesc g[3]; int n; };

__global__ __launch_bounds__(256)
void gemm_grouped(GArgs ga)
{
    __shared__ float          As_f[2][4096];
    __shared__ unsigned short Bs[2][4096];
    __shared__ float scL[256], shL[256];
    unsigned short* As_b = (unsigned short*)&As_f[0][0];

    const int bid = blockIdx.x;
    int gi = 0;
    #pragma unroll
    for (int i = 1; i < 3; ++i)
        if (i < ga.n && bid >= ga.g[i].block0) gi = i;
    const GDesc d = ga.g[gi];

    int local = bid - d.block0;
    {
        const int cpx = (d.nbb * d.ksplit) >> 3;
        local = (local & 7) * cpx + (local >> 3);
    }
    int kc = 0;
    int Kc = d.K;
    if (d.ksplit > 1) {
        Kc = d.K / d.ksplit;
        kc = local / d.nbb;
        local -= kc * d.nbb;
    }
    const int kbeg = kc * Kc;
    const int bx = local % d.nbx;
    const int by = local / d.nbx;
    const int row0 = by * 128;
    const int col0 = bx * 128;

    const int tid  = threadIdx.x;
    const int wave = tid >> 6;
    const int lane = tid & 63;
    const int qd   = lane >> 4;
    const int ln   = lane & 15;
    const int wr   = (wave >> 1) * 64;
    const int wc   = (wave & 1) * 64;

    const int c0 = wave * 128 + lane;
    const int c1 = c0 + 64;
    const int r0 = c0 >> 2, k0 = (((c0 & 3) ^ ((c0 >> 3) & 3))) * 8;
    const int r1 = c1 >> 2, k1 = (((c1 & 3) ^ ((c1 >> 3) & 3))) * 8;

    const int aro  = wave * 32 + (lane >> 3);
    const int acol = ((lane & 7) ^ (lane >> 3)) * 4;

    const bool afp = (d.Af != nullptr);
    const int niter = Kc >> 5;

    floatx4 acc[4][4];
    #pragma unroll
    for (int i = 0; i < 4; ++i)
        #pragma unroll
        for (int j = 0; j < 4; ++j) acc[i][j] = (floatx4){0.f, 0.f, 0.f, 0.f};

    if (d.fuseA) {
        for (int k = tid; k < Kc; k += 256) {
            float sc = d.g[kbeg + k] * rsqrtf(d.v[kbeg + k] + 1e-5f);
            scL[k] = sc;
            shL[k] = d.b[kbeg + k] - d.m[kbeg + k] * sc;
        }
    }
    g2l16(d.W + (size_t)(col0 + r0) * d.K + kbeg + k0, &Bs[0][(size_t)wave * 1024]);
    g2l16(d.W + (size_t)(col0 + r1) * d.K + kbeg + k1, &Bs[0][(size_t)wave * 1024 + 512]);
    if (afp) {
        #pragma unroll
        for (int t = 0; t < 4; ++t)
            g2l16(d.Af + (size_t)(row0 + aro + t * 8) * d.Kreal + kbeg + acol,
                  &As_f[0][(size_t)(wave * 4 + t) * 256]);
    } else {
        g2l16(d.Ab + (size_t)(row0 + r0) * d.K + kbeg + k0, As_b + (size_t)wave * 1024);
        g2l16(d.Ab + (size_t)(row0 + r1) * d.K + kbeg + k1, As_b + (size_t)wave * 1024 + 512);
    }
    __syncthreads();

    int cur = 0;
    for (int it = 0; it < niter; ++it) {
        const int nxt = cur ^ 1;
        const bool pf = (it + 1 < niter);

        if (pf) {
            const int kg = kbeg + (it + 1) * 32;
            g2l16(d.W + (size_t)(col0 + r0) * d.K + kg + k0, &Bs[nxt][(size_t)wave * 1024]);
            g2l16(d.W + (size_t)(col0 + r1) * d.K + kg + k1, &Bs[nxt][(size_t)wave * 1024 + 512]);
            if (afp) {
                #pragma unroll
                for (int t = 0; t < 4; ++t)
                    g2l16(d.Af + (size_t)(row0 + aro + t * 8) * d.Kreal + kg + acol,
                          &As_f[nxt][(size_t)(wave * 4 + t) * 256]);
            } else {
                g2l16(d.Ab + (size_t)(row0 + r0) * d.K + kg + k0, As_b + (size_t)nxt * 4096 + wave * 1024);
                g2l16(d.Ab + (size_t)(row0 + r1) * d.K + kg + k1, As_b + (size_t)nxt * 4096 + wave * 1024 + 512);
            }
        }

        short8 a[4], b[4];
        if (afp) {
            const int kl = it * 32;
            #pragma unroll
            for (int i = 0; i < 4; ++i) {
                const int row = wr + i * 16 + ln;
                const int sw  = row & 7;
                const int c0f = ((qd * 2)     ^ sw) * 4;
                const int c1f = ((qd * 2 + 1) ^ sw) * 4;
                float4 v0 = *(const float4*)&As_f[cur][row * 32 + c0f];
                float4 v1 = *(const float4*)&As_f[cur][row * 32 + c1f];
                if (d.fuseA) {
                    const int kf = kl + qd * 8;            // TRUE k of v0
                    v0 = bnrelu4(v0, *(const float4*)&scL[kf],
                                     *(const float4*)&shL[kf]);
                    v1 = bnrelu4(v1, *(const float4*)&scL[kf + 4],
                                     *(const float4*)&shL[kf + 4]);
                }
                int4 pk = { (int)pk_bf16(v0.x, v0.y), (int)pk_bf16(v0.z, v0.w),
                            (int)pk_bf16(v1.x, v1.y), (int)pk_bf16(v1.z, v1.w) };
                a[i] = *(short8*)&pk;
            }
        } else {
            #pragma unroll
            for (int i = 0; i < 4; ++i) {
                const int row = wr + i * 16 + ln;
                const int sw  = (row >> 1) & 3;
                a[i] = *(const short8*)&As_b[(size_t)cur * 4096 + row * 32 + (qd ^ sw) * 8];
            }
        }
        #pragma unroll
        for (int j = 0; j < 4; ++j) {
            const int row = wc + j * 16 + ln;
            const int sw  = (row >> 1) & 3;
            b[j] = *(const short8*)&Bs[cur][row * 32 + (qd ^ sw) * 8];
        }
        #pragma unroll
        for (int i = 0; i < 4; ++i)
            #pragma unroll
            for (int j = 0; j < 4; ++j)
                acc[i][j] = __builtin_amdgcn_mfma_f32_16x16x32_bf16(
                                a[i], b[j], acc[i][j], 0, 0, 0);

        __syncthreads();
        cur = nxt;
    }

    if (d.ksplit > 1) {
        #pragma unroll
        for (int j = 0; j < 4; ++j) {
            const int col = col0 + wc + j * 16 + ln;
            #pragma unroll
            for (int i = 0; i < 4; ++i) {
                #pragma unroll
                for (int r = 0; r < 4; ++r) {
                    const int row = row0 + wr + i * 16 + qd * 4 + r;
                    atomicAdd(&d.Cf[(size_t)row * d.N + col], acc[i][j][r]);
                }
            }
        }
        return;
    }

    #pragma unroll
    for (int j = 0; j < 4; ++j) {
        const int col = col0 + wc + j * 16 + ln;
        float add = d.bias ? d.bias[col] : 0.f;
        float scale = 1.f, shift = 0.f;
        if (d.fuse) {
            scale = d.g[col] * rsqrtf(d.v[col] + 1e-5f);
            shift = d.b[col] - d.m[col] * scale;
        }
        #pragma unroll
        for (int i = 0; i < 4; ++i) {
            #pragma unroll
            for (int r = 0; r < 4; ++r) {
                const int row = row0 + wr + i * 16 + qd * 4 + r;
                float vv = acc[i][j][r] + add;
                if (d.fuse) vv = fmaxf(vv * scale + shift, 0.f);
                if (d.Cf) d.Cf[(size_t)row * d.N + col] = vv;
                if (d.Cb) d.Cb[(size_t)row * d.N + col] = f2bf(vv);
            }
        }
    }
}

// ---------------------------------------------------------------------------
// Prep kernel (r9): 6 GEMM weights fp32 -> bf16; Wf -> packed-transposed
// u32[352][256]; zero-fill the atomic-accumulator span.
// ---------------------------------------------------------------------------
struct WSeg { const float* src; void* dst; int Kreal; int Kp; };
struct WArgs { WSeg s[7]; int off[8]; float4* zdst; int zn; };

__global__ __launch_bounds__(256)
void cvt_weights(WArgs wa)
{
    int i = blockIdx.x * 256 + threadIdx.x;
    if (i >= wa.off[7]) {
        int z = i - wa.off[7];
        if (z < wa.zn) wa.zdst[z] = (float4){0.f, 0.f, 0.f, 0.f};
        return;
    }
    int s = 0;
    #pragma unroll
    for (int j = 1; j < 7; ++j) if (i >= wa.off[j]) s = j;
    const WSeg sg = wa.s[s];
    const int li = i - wa.off[s];
    if (s == 6) {
        const int k2 = li >> 8, c = li & 255;
        const int ka = k2 * 2, kb = k2 * 2 + 1;
        unsigned int lo = (ka < 688) ? f2bf(sg.src[(size_t)c * 688 + ka]) : 0u;
        unsigned int hi = (kb < 688) ? f2bf(sg.src[(size_t)c * 688 + kb]) : 0u;
        ((unsigned int*)sg.dst)[li] = lo | (hi << 16);
        return;
    }
    const int r = li / sg.Kp, c = li - r * sg.Kp;
    ((unsigned short*)sg.dst)[li] =
        (c < sg.Kreal) ? f2bf(sg.src[(size_t)r * sg.Kreal + c]) : (unsigned short)0;
}

// ---------------------------------------------------------------------------
// Fused attention (r9): channel attn + spatial conv + sum over N + fc1.
// IDEMPOTENT (pure function of inputs -> out); launched 5x this round as
// instrumentation: T_attn = (wall - 495)/4.
// ---------------------------------------------------------------------------
__global__ __launch_bounds__(256)
void attn_kernel(const float* __restrict__ obj, const float* __restrict__ bbox,
                 const float* __restrict__ word, const float* __restrict__ sen,
                 const float* __restrict__ bod,
                 const float* __restrict__ Wc1, const float* __restrict__ Wc2,
                 const float* __restrict__ Wsa,
                 const unsigned int* __restrict__ wfpk,
                 const float* __restrict__ bf,
                 const float* __restrict__ g_f, const float* __restrict__ b_f,
                 const float* __restrict__ m_f, const float* __restrict__ v_f,
                 float* __restrict__ out)
{
    const int b = blockIdx.x;
    const int tid = threadIdx.x;

    __shared__ float xs[10][688];
    __shared__ float s0[688], s1[688];
    __shared__ float xr[688];
    __shared__ float avec[10], mvec[10], att[10];
    __shared__ float cw[14], c1[50], c2[50];

    if (tid < 14) cw[tid] = Wsa[tid];
    if (tid < 50) { c1[tid] = Wc1[tid]; c2[tid] = Wc2[tid]; }

    for (int n = 0; n < 10; ++n) {
        const float* o  = obj  + ((size_t)b * 10 + n) * 128;
        const float* bx = bbox + ((size_t)b * 10 + n) * 4;
        const float* w  = word + ((size_t)b * 10 + n) * 300;
        const float* s  = sen  + ((size_t)b * 10 + n) * 128;
        const float* bo = bod  + (size_t)b * 128;
        for (int c = tid; c < 688; c += 256) {
            float v;
            if      (c < 128) v = o[c];
            else if (c < 132) v = bx[c - 128];
            else if (c < 432) v = w[c - 132];
            else if (c < 560) v = s[c - 432];
            else              v = bo[c - 560];
            xs[n][c] = v;
        }
    }
    __syncthreads();

    {
        const int wv = tid >> 6, ln2 = tid & 63;
        for (int n = wv; n < 10; n += 4) {
            float sm = 0.f, mx = -INFINITY;
            for (int c = ln2; c < 688; c += 64) {
                float v = xs[n][c];
                sm += v; mx = fmaxf(mx, v);
            }
            #pragma unroll
            for (int off = 32; off > 0; off >>= 1) {
                sm += __shfl_down(sm, off);
                mx = fmaxf(mx, __shfl_down(mx, off));
            }
            if (ln2 == 0) { avec[n] = sm * (1.f / 688.f); mvec[n] = mx; }
        }
    }
    __syncthreads();

    if (tid == 0) {
        float ha[5], hm[5];
        #pragma unroll
        for (int i = 0; i < 5; ++i) {
            float sa_ = 0.f, sm_ = 0.f;
            #pragma unroll
            for (int j = 0; j < 10; ++j) {
                sa_ += c1[i * 10 + j] * avec[j];
                sm_ += c1[i * 10 + j] * mvec[j];
            }
            ha[i] = fmaxf(sa_, 0.f);
            hm[i] = fmaxf(sm_, 0.f);
        }
        #pragma unroll
        for (int j = 0; j < 10; ++j) {
            float v = 0.f;
            #pragma unroll
            for (int i = 0; i < 5; ++i) v += c2[j * 5 + i] * (ha[i] + hm[i]);
            att[j] = 1.f / (1.f + expf(-v));
        }
    }
    __syncthreads();

    for (int c = tid; c < 688; c += 256) {
        float sm = 0.f, mx = -INFINITY;
        #pragma unroll
        for (int n = 0; n < 10; ++n) {
            float v = xs[n][c] * att[n];
            xs[n][c] = v;
            sm += v; mx = fmaxf(mx, v);
        }
        s0[c] = sm * 0.1f;
        s1[c] = mx;
    }
    __syncthreads();

    for (int c = tid; c < 688; c += 256) {
        float sa = 0.f;
        #pragma unroll
        for (int j = 0; j < 7; ++j) {
            int cc = c + j - 3;
            if (cc >= 0 && cc < 688)
                sa += cw[j] * s0[cc] + cw[7 + j] * s1[cc];
        }
        float sig = 1.f / (1.f + expf(-sa));
        float sm = 0.f;
        #pragma unroll
        for (int n = 0; n < 10; ++n) sm += xs[n][c];
        xr[c] = sm * sig;
    }
    __syncthreads();

    {
        float acc = 0.f;
        #pragma unroll 4
        for (int k2 = 0; k2 < 344; ++k2) {
            unsigned int w2 = wfpk[(size_t)k2 * 256 + tid];
            acc += __uint_as_float(w2 << 16)         * xr[2 * k2]
                 + __uint_as_float(w2 & 0xffff0000u) * xr[2 * k2 + 1];
        }
        float sc = g_f[tid] * rsqrtf(v_f[tid] + 1e-5f);
        float sh = b_f[tid] - m_f[tid] * sc;
        out[(size_t)b * 256 + tid] = fmaxf((acc + bf[tid]) * sc + sh, 0.f);
    }
}

// ---------------------------------------------------------------------------
extern "C" void kernel_launch(void* const* d_in, const int* in_sizes, int n_in,
                              void* d_out, int out_size, void* d_ws, size_t ws_size,
                              hipStream_t stream)
{
    const float* f_obj = (const float*)d_in[0];
    const float* bbox  = (const float*)d_in[1];
    const float* word  = (const float*)d_in[2];
    const float* sent  = (const float*)d_in[3];
    const float* body  = (const float*)d_in[4];
    const float* W1_o  = (const float*)d_in[5];
    const float* g_o = (const float*)d_in[6],  *b_o = (const float*)d_in[7];
    const float* m_o = (const float*)d_in[8],  *v_o = (const float*)d_in[9];
    const float* W2_o  = (const float*)d_in[10];
    const float* W1_s  = (const float*)d_in[11];
    const float* g_s = (const float*)d_in[12], *b_s = (const float*)d_in[13];
    const float* m_s = (const float*)d_in[14], *v_s = (const float*)d_in[15];
    const float* W2_s  = (const float*)d_in[16];
    const float* W1_b  = (const float*)d_in[17];
    const float* g_b = (const float*)d_in[18], *b_b = (const float*)d_in[19];
    const float* m_b = (const float*)d_in[20], *v_b = (const float*)d_in[21];
    const float* W2_b  = (const float*)d_in[22];
    const float* Wc1 = (const float*)d_in[23];
    const float* Wc2 = (const float*)d_in[24];
    const float* Wsa = (const float*)d_in[25];
    const float* Wf  = (const float*)d_in[26];
    const float* bf  = (const float*)d_in[27];
    const float* g_f = (const float*)d_in[28], *b_f = (const float*)d_in[29];
    const float* m_f = (const float*)d_in[30], *v_f = (const float*)d_in[31];
    float* out = (float*)d_out;

    // ---- workspace carve (~44.4 MB) ----
    char* p = (char*)d_ws;
    unsigned short* w1s  = (unsigned short*)p; p += 4194304;   // 512*4096
    unsigned short* w2s  = (unsigned short*)p; p += 131072;    // 128*512
    unsigned short* w1o  = (unsigned short*)p; p += 262144;    // 128*1024
    unsigned short* w2o  = (unsigned short*)p; p += 32768;     // 128*128
    unsigned short* w1b  = (unsigned short*)p; p += 1048576;   // 256*2048
    unsigned short* w2b  = (unsigned short*)p; p += 65536;     // 128*256
    unsigned int*   wfpk = (unsigned int*)p;   p += 360448;    // 352*256 u32
    char* zbase = p;
    float* sen_f = (float*)p; p += 5242880;                    // 10240*128 f32
    float* obj_f = (float*)p; p += 5242880;                    // 10240*128 f32
    float* bod_f = (float*)p; p += 524288;                     // 1024*128 f32
    float* ps    = (float*)p; p += 20971520;                   // 10240*512 f32
    float* po    = (float*)p; p += 5242880;                    // 10240*128 f32
    float* pb    = (float*)p; p += 1048576;                    // 1024*256 f32
    const int zbytes = 38273024;
    if ((size_t)(p - (char*)d_ws) > ws_size) return;

    // ---- 1) weights -> bf16 / packed Wf + zero atomic span ----
    WArgs wa;
    wa.s[0] = { W1_s, w1s,  4096, 4096 };
    wa.s[1] = { W2_s, w2s,   512,  512 };
    wa.s[2] = { W1_o, w1o,  1024, 1024 };
    wa.s[3] = { W2_o, w2o,   128,  128 };
    wa.s[4] = { W1_b, w1b,  2048, 2048 };
    wa.s[5] = { W2_b, w2b,   256,  256 };
    wa.s[6] = { Wf,   wfpk,  688,  704 };
    const int wn[7] = { 512*4096, 128*512, 128*1024, 128*128, 256*2048, 128*256, 352*256 };
    wa.off[0] = 0;
    for (int i = 0; i < 7; ++i) wa.off[i + 1] = wa.off[i] + wn[i];
    wa.zdst = (float4*)zbase;
    wa.zn   = zbytes / 16;
    cvt_weights<<<(wa.off[7] + wa.zn + 255) / 256, 256, 0, stream>>>(wa);

    // ---- 2) stage-1 grouped GEMM, split-K x2 ----
    {
        GArgs ga; ga.n = 3;
        ga.g[0] = { sent,  nullptr, w1s, ps, nullptr, nullptr, nullptr, nullptr, nullptr, nullptr,
                    10240, 512, 4096, 4096, 0, 4, 0,   320, 2, 0 };
        ga.g[1] = { f_obj, nullptr, w1o, po, nullptr, nullptr, nullptr, nullptr, nullptr, nullptr,
                    10240, 128, 1024, 1024, 0, 1, 640, 80,  2, 0 };
        ga.g[2] = { body,  nullptr, w1b, pb, nullptr, nullptr, nullptr, nullptr, nullptr, nullptr,
                    1024,  256, 2048, 2048, 0, 2, 800, 16,  2, 0 };
        gemm_grouped<<<832, 256, 0, stream>>>(ga);
    }

    // ---- 3) stage-2 grouped GEMM: fused input-BN+ReLU, split-K x2 ----
    {
        GArgs ga; ga.n = 3;
        ga.g[0] = { ps, nullptr, w2s, sen_f, nullptr, nullptr, g_s, b_s, m_s, v_s,
                    10240, 128, 512, 512, 0, 1, 0,   80, 2, 1 };
        ga.g[1] = { po, nullptr, w2o, obj_f, nullptr, nullptr, g_o, b_o, m_o, v_o,
                    10240, 128, 128, 128, 0, 1, 160, 80, 2, 1 };
        ga.g[2] = { pb, nullptr, w2b, bod_f, nullptr, nullptr, g_b, b_b, m_b, v_b,
                    1024,  128, 256, 256, 0, 1, 320, 8,  2, 1 };
        gemm_grouped<<<336, 256, 0, stream>>>(ga);
    }

    // ---- 4) attn: launched 5x (idempotent) as instrumentation this round:
    //      T_attn = (wall - 495)/4; surfaces in top-5 if > ~160 us ----
    for (int rep = 0; rep < 5; ++rep)
        attn_kernel<<<1024, 256, 0, stream>>>(obj_f, bbox, word, sen_f, bod_f,
                                              Wc1, Wc2, Wsa, wfpk, bf,
                                              g_f, b_f, m_f, v_f, out);
}